// Round 1
// baseline (20693.423 us; speedup 1.0000x reference)
//
#include <hip/hip_runtime.h>
#include <cstddef>

static constexpr int B_ = 8;
static constexpr int H_ = 256;
static constexpr int W_ = 256;
static constexpr int HW_ = H_ * W_;

// ---------------------------------------------------------------------------
// Mask kernel: cnt = clamp(cin * boxsum3x3_dil(m), 1e-5), mnew = maxpool3x3_dil(m)
// Zero padding => OOB taps contribute 0 to both sum and max (mask values >= 0).
// ---------------------------------------------------------------------------
__global__ void mask_kernel(const float* __restrict__ m, float* __restrict__ cnt,
                            float* __restrict__ mnew, int d, float cin) {
  int idx = blockIdx.x * 256 + threadIdx.x;            // b*HW + h*W + w
  int b = idx >> 16;
  int hw = idx & (HW_ - 1);
  int h = hw >> 8, w = hw & (W_ - 1);
  const float* mb = m + b * HW_;
  float s = 0.f, mx = 0.f;
#pragma unroll
  for (int kh = 0; kh < 3; ++kh) {
    int hh = h + (kh - 1) * d;
    if ((unsigned)hh >= (unsigned)H_) continue;
#pragma unroll
    for (int kw = 0; kw < 3; ++kw) {
      int ww = w + (kw - 1) * d;
      if ((unsigned)ww >= (unsigned)W_) continue;
      float v = mb[hh * W_ + ww];
      s += v;
      mx = fmaxf(mx, v);
    }
  }
  cnt[idx] = fmaxf(s * cin, 1e-5f);
  mnew[idx] = mx;
}

// ---------------------------------------------------------------------------
// Direct 3x3 dilated conv on masked input, fused /cnt + bias epilogue and
// fused BN statistics (sum, sumsq) reduction. Each 256-thread block covers
// one (b, co, h, :) row -> single channel per block -> 2 atomicAdds/block.
// ---------------------------------------------------------------------------
template <int CIN>
__global__ void conv3x3_kernel(const float* __restrict__ x, const float* __restrict__ m,
                               const float* __restrict__ cnt, const float* __restrict__ Wt,
                               const float* __restrict__ bias, float* __restrict__ y,
                               float* __restrict__ stats, int Cout, int d) {
  int w = threadIdx.x;       // 0..255
  int h = blockIdx.x;        // 0..255
  int bc = blockIdx.y;       // b*Cout + co
  int co = bc % Cout;
  int b = bc / Cout;

  __shared__ float wl[CIN * 9];
  for (int i = threadIdx.x; i < CIN * 9; i += 256)
    wl[i] = Wt[(size_t)co * CIN * 9 + i];
  __syncthreads();

  const float* xb = x + (size_t)b * CIN * HW_;
  const float* mb = m + b * HW_;
  float acc = 0.f;
#pragma unroll
  for (int kh = 0; kh < 3; ++kh) {
    int hh = h + (kh - 1) * d;
    if ((unsigned)hh >= (unsigned)H_) continue;
#pragma unroll
    for (int kw = 0; kw < 3; ++kw) {
      int ww = w + (kw - 1) * d;
      if ((unsigned)ww >= (unsigned)W_) continue;
      float mv = mb[hh * W_ + ww];
      if (mv == 0.f) continue;           // mask sparsity skip (cin-deep work saved)
      const float* xp = xb + hh * W_ + ww;
      const float* wp = wl + kh * 3 + kw;
      float t = 0.f;
#pragma unroll 8
      for (int ci = 0; ci < CIN; ++ci)
        t = fmaf(xp[(size_t)ci * HW_], wp[ci * 9], t);
      acc = fmaf(mv, t, acc);
    }
  }

  float r = acc / cnt[b * HW_ + h * W_ + w] + bias[co];
  y[(size_t)bc * HW_ + h * W_ + w] = r;

  // BN stats: wave shuffle reduce (width 64) -> LDS across 4 waves -> atomics
  float s = r, q = r * r;
#pragma unroll
  for (int off = 32; off > 0; off >>= 1) {
    s += __shfl_down(s, off, 64);
    q += __shfl_down(q, off, 64);
  }
  __shared__ float ps[4], pq[4];
  int wave = threadIdx.x >> 6;
  if ((threadIdx.x & 63) == 0) { ps[wave] = s; pq[wave] = q; }
  __syncthreads();
  if (threadIdx.x == 0) {
    atomicAdd(&stats[2 * co],     ps[0] + ps[1] + ps[2] + ps[3]);
    atomicAdd(&stats[2 * co + 1], pq[0] + pq[1] + pq[2] + pq[3]);
  }
}

// Fold BN (batch stats, biased var) + gamma/beta into per-channel scale+shift.
__global__ void bn_prep(float* __restrict__ stats, const float* __restrict__ g,
                        const float* __restrict__ be, int C, float invN) {
  int c = threadIdx.x;
  if (c >= C) return;
  float mean = stats[2 * c] * invN;
  float var = stats[2 * c + 1] * invN - mean * mean;   // biased variance
  float a = g[c] * rsqrtf(var + 1e-5f);
  stats[2 * c] = a;
  stats[2 * c + 1] = be[c] - a * mean;
}

// In-place BN apply + LeakyReLU, float4-vectorized. C is a power of two.
__global__ void bn_apply(float4* __restrict__ y, const float* __restrict__ stats, int C) {
  size_t idx = (size_t)blockIdx.x * 256 + threadIdx.x;   // float4 index
  int c = (int)((idx >> 14) & (size_t)(C - 1));          // (idx*4 / HW) % C
  float a = stats[2 * c], bb = stats[2 * c + 1];
  float4 v = y[idx];
  v.x = fmaf(a, v.x, bb); v.y = fmaf(a, v.y, bb);
  v.z = fmaf(a, v.z, bb); v.w = fmaf(a, v.w, bb);
  v.x = v.x >= 0.f ? v.x : 0.01f * v.x;
  v.y = v.y >= 0.f ? v.y : 0.01f * v.y;
  v.z = v.z >= 0.f ? v.z : 0.01f * v.z;
  v.w = v.w >= 0.f ? v.w : 0.01f * v.w;
  y[idx] = v;
}

// Final 1x1 conv: 128 -> 64 channels, straight into d_out.
__global__ void conv1x1_kernel(const float* __restrict__ x, const float* __restrict__ Wf,
                               const float* __restrict__ bfv, float* __restrict__ out) {
  int w = threadIdx.x;
  int h = blockIdx.x;
  int bc = blockIdx.y;          // b*64 + co
  int b = bc >> 6, co = bc & 63;
  __shared__ float wl[128];
  if (threadIdx.x < 128) wl[threadIdx.x] = Wf[co * 128 + threadIdx.x];
  __syncthreads();
  const float* xb = x + (size_t)b * 128 * HW_ + h * W_ + w;
  float acc = bfv[co];
#pragma unroll 16
  for (int ci = 0; ci < 128; ++ci)
    acc = fmaf(xb[(size_t)ci * HW_], wl[ci], acc);
  out[(size_t)bc * HW_ + h * W_ + w] = acc;
}

__global__ void copy4_kernel(const float4* __restrict__ src, float4* __restrict__ dst) {
  int idx = blockIdx.x * 256 + threadIdx.x;
  dst[idx] = src[idx];
}

// ---------------------------------------------------------------------------
extern "C" void kernel_launch(void* const* d_in, const int* in_sizes, int n_in,
                              void* d_out, int out_size, void* d_ws, size_t ws_size,
                              hipStream_t stream) {
  const float* feat = (const float*)d_in[0];
  const float* mask = (const float*)d_in[1];
  const float *Wl[5], *bl[5], *gl[5], *bel[5];
  for (int l = 0; l < 5; ++l) {
    Wl[l]  = (const float*)d_in[2 + 4 * l];
    bl[l]  = (const float*)d_in[3 + 4 * l];
    gl[l]  = (const float*)d_in[4 + 4 * l];
    bel[l] = (const float*)d_in[5 + 4 * l];
  }
  const float* Wf = (const float*)d_in[22];
  const float* bf = (const float*)d_in[23];

  // Workspace layout (floats):
  //   bufA: 8*128*HW   (largest outputs: blocks 0,2,4)
  //   bufB: 8*64*HW    (blocks 1,3)
  //   maskA, maskB, cnt: 8*HW each; stats: 256
  float* ws = (float*)d_ws;
  float* bufA = ws;
  float* bufB = bufA + (size_t)B_ * 128 * HW_;
  float* maskA = bufB + (size_t)B_ * 64 * HW_;
  float* maskB = maskA + (size_t)B_ * HW_;
  float* cntb = maskB + (size_t)B_ * HW_;
  float* stats = cntb + (size_t)B_ * HW_;

  static const int DIMS[5] = {16, 32, 64, 64, 128};
  static const int DILS[5] = {1, 2, 1, 2, 1};

  const float* xin = feat;
  int cin = 32;
  const float* mcur = mask;
  float* fb[2] = {bufA, bufB};
  float* mbuf[2] = {maskA, maskB};

  for (int l = 0; l < 5; ++l) {
    int d = DILS[l], cout = DIMS[l];
    float* yout = fb[l & 1];      // A,B,A,B,A — sizes fit by construction
    float* mnext = mbuf[l & 1];   // A,B,A,B,A — final mask lands in maskA

    hipMemsetAsync(stats, 0, 2 * cout * sizeof(float), stream);
    mask_kernel<<<(B_ * HW_) / 256, 256, 0, stream>>>(mcur, cntb, mnext, d, (float)cin);

    dim3 grid(H_, B_ * cout);
    switch (cin) {
      case 16: conv3x3_kernel<16><<<grid, 256, 0, stream>>>(xin, mcur, cntb, Wl[l], bl[l], yout, stats, cout, d); break;
      case 32: conv3x3_kernel<32><<<grid, 256, 0, stream>>>(xin, mcur, cntb, Wl[l], bl[l], yout, stats, cout, d); break;
      case 64: conv3x3_kernel<64><<<grid, 256, 0, stream>>>(xin, mcur, cntb, Wl[l], bl[l], yout, stats, cout, d); break;
    }

    bn_prep<<<1, 128, 0, stream>>>(stats, gl[l], bel[l], cout, 1.f / (float)(B_ * HW_));
    size_t nvec = (size_t)B_ * cout * HW_ / 4;
    bn_apply<<<(unsigned)(nvec / 256), 256, 0, stream>>>((float4*)yout, stats, cout);

    xin = yout;
    cin = cout;
    mcur = mnext;
  }

  conv1x1_kernel<<<dim3(H_, B_ * 64), 256, 0, stream>>>(xin, Wf, bf, (float*)d_out);
  copy4_kernel<<<(B_ * HW_ / 4) / 256, 256, 0, stream>>>(
      (const float4*)mcur, (float4*)d_out + ((size_t)B_ * 64 * HW_) / 4);
}

// Round 2
// 3447.900 us; speedup vs baseline: 6.0017x; 6.0017x over previous
//
#include <hip/hip_runtime.h>
#include <cstddef>

static constexpr int B_ = 8;
static constexpr int H_ = 256;
static constexpr int W_ = 256;
static constexpr int HW_ = H_ * W_;

// ---------------------------------------------------------------------------
// Mask kernel: cnt = clamp(cin * boxsum3x3_dil(m), 1e-5), mnew = maxpool3x3_dil(m)
// ---------------------------------------------------------------------------
__global__ void mask_kernel(const float* __restrict__ m, float* __restrict__ cnt,
                            float* __restrict__ mnew, int d, float cin) {
  int idx = blockIdx.x * 256 + threadIdx.x;            // b*HW + h*W + w
  int b = idx >> 16;
  int hw = idx & (HW_ - 1);
  int h = hw >> 8, w = hw & (W_ - 1);
  const float* mb = m + b * HW_;
  float s = 0.f, mx = 0.f;
#pragma unroll
  for (int kh = 0; kh < 3; ++kh) {
    int hh = h + (kh - 1) * d;
    if ((unsigned)hh >= (unsigned)H_) continue;
#pragma unroll
    for (int kw = 0; kw < 3; ++kw) {
      int ww = w + (kw - 1) * d;
      if ((unsigned)ww >= (unsigned)W_) continue;
      float v = mb[hh * W_ + ww];
      s += v;
      mx = fmaxf(mx, v);
    }
  }
  cnt[idx] = fmaxf(s * cin, 1e-5f);
  mnew[idx] = mx;
}

// ---------------------------------------------------------------------------
// Weight transpose: Wt[co][k] -> Wt_t[k][co], k = ci*9 + tap (or ci for 1x1).
// ---------------------------------------------------------------------------
__global__ void transpose_w(const float* __restrict__ Wt, float* __restrict__ Wt_t,
                            int cout, int cink) {
  int i = blockIdx.x * 256 + threadIdx.x;
  if (i >= cout * cink) return;
  int co = i / cink, k = i % cink;
  Wt_t[k * cout + co] = Wt[i];
}

// ---------------------------------------------------------------------------
// Register-tiled direct 3x3 dilated conv on masked input.
// Each thread: 2 rows (h0, h0+1) x 16 output channels. Weights staged in LDS
// transposed to [(ci*9+t)][16] so 16 co-weights come from one float4 pair.
// Epilogue: /cnt + bias.
// ---------------------------------------------------------------------------
template <int CIN>
__global__ __launch_bounds__(256) void conv3x3_rt(
    const float* __restrict__ x, const float* __restrict__ m,
    const float* __restrict__ cnt, const float* __restrict__ Wt_t,
    const float* __restrict__ bias, float* __restrict__ y,
    int cout, int d, int G) {
  constexpr int COT = 16;
  int w = threadIdx.x;
  int h0 = blockIdx.x * 2;
  int g = blockIdx.y % G;
  int b = blockIdx.y / G;
  int co0 = g * COT;

  extern __shared__ float wsm[];                 // CIN*9*COT floats
  for (int i = threadIdx.x; i < CIN * 9 * COT; i += 256) {
    int ct = i / COT, j = i % COT;
    wsm[i] = Wt_t[ct * cout + co0 + j];
  }
  __syncthreads();

  const float* mb = m + b * HW_;
  float mv[2][9];
  int off[2][9];
#pragma unroll
  for (int p = 0; p < 2; ++p) {
    int h = h0 + p;
#pragma unroll
    for (int kh = 0; kh < 3; ++kh) {
      int hh = h + (kh - 1) * d;
#pragma unroll
      for (int kw = 0; kw < 3; ++kw) {
        int ww = w + (kw - 1) * d;
        int t = kh * 3 + kw;
        bool v = ((unsigned)hh < (unsigned)H_) && ((unsigned)ww < (unsigned)W_);
        off[p][t] = v ? hh * W_ + ww : 0;
        mv[p][t] = v ? mb[hh * W_ + ww] : 0.f;
      }
    }
  }

  float acc[2][COT];
#pragma unroll
  for (int p = 0; p < 2; ++p)
#pragma unroll
    for (int j = 0; j < COT; ++j) acc[p][j] = 0.f;

  const float* xb = x + (size_t)b * CIN * HW_;
  for (int ci = 0; ci < CIN; ++ci) {
    const float* xc = xb + (size_t)ci * HW_;
    float xm[2][9];
#pragma unroll
    for (int p = 0; p < 2; ++p)
#pragma unroll
      for (int t = 0; t < 9; ++t)
        xm[p][t] = xc[off[p][t]] * mv[p][t];
    const float* wr = wsm + ci * 9 * COT;
#pragma unroll
    for (int t = 0; t < 9; ++t) {
#pragma unroll
      for (int jj = 0; jj < COT / 4; ++jj) {
        float4 wv = *(const float4*)(wr + t * COT + jj * 4);
#pragma unroll
        for (int p = 0; p < 2; ++p) {
          acc[p][jj * 4 + 0] = fmaf(wv.x, xm[p][t], acc[p][jj * 4 + 0]);
          acc[p][jj * 4 + 1] = fmaf(wv.y, xm[p][t], acc[p][jj * 4 + 1]);
          acc[p][jj * 4 + 2] = fmaf(wv.z, xm[p][t], acc[p][jj * 4 + 2]);
          acc[p][jj * 4 + 3] = fmaf(wv.w, xm[p][t], acc[p][jj * 4 + 3]);
        }
      }
    }
  }

#pragma unroll
  for (int p = 0; p < 2; ++p) {
    int h = h0 + p;
    float inv = 1.0f / cnt[b * HW_ + h * W_ + w];
#pragma unroll
    for (int j = 0; j < COT; ++j) {
      float r = acc[p][j] * inv + bias[co0 + j];
      y[((size_t)b * cout + co0 + j) * HW_ + h * W_ + w] = r;
    }
  }
}

// ---------------------------------------------------------------------------
// Per-channel BN stats: sum and sumsq, float4 reads, wave+LDS reduce, atomics.
// grid = (HW/1024, B*cout), 256 threads, 1 float4 per thread.
// ---------------------------------------------------------------------------
__global__ void stats_kernel(const float4* __restrict__ y, float* __restrict__ stats,
                             int cout) {
  int c = blockIdx.y % cout;
  size_t idx = (size_t)blockIdx.y * (HW_ / 4) + blockIdx.x * 256 + threadIdx.x;
  float4 v = y[idx];
  float s = v.x + v.y + v.z + v.w;
  float q = v.x * v.x + v.y * v.y + v.z * v.z + v.w * v.w;
#pragma unroll
  for (int off = 32; off > 0; off >>= 1) {
    s += __shfl_down(s, off, 64);
    q += __shfl_down(q, off, 64);
  }
  __shared__ float ps[4], pq[4];
  int wave = threadIdx.x >> 6;
  if ((threadIdx.x & 63) == 0) { ps[wave] = s; pq[wave] = q; }
  __syncthreads();
  if (threadIdx.x == 0) {
    atomicAdd(&stats[2 * c], ps[0] + ps[1] + ps[2] + ps[3]);
    atomicAdd(&stats[2 * c + 1], pq[0] + pq[1] + pq[2] + pq[3]);
  }
}

// Fold BN (batch stats, biased var) + gamma/beta into per-channel scale+shift.
__global__ void bn_prep(float* __restrict__ stats, const float* __restrict__ g,
                        const float* __restrict__ be, int C, float invN) {
  int c = threadIdx.x;
  if (c >= C) return;
  float mean = stats[2 * c] * invN;
  float var = stats[2 * c + 1] * invN - mean * mean;
  float a = g[c] * rsqrtf(var + 1e-5f);
  stats[2 * c] = a;
  stats[2 * c + 1] = be[c] - a * mean;
}

// In-place BN apply + LeakyReLU, float4-vectorized. C is a power of two.
__global__ void bn_apply(float4* __restrict__ y, const float* __restrict__ stats, int C) {
  size_t idx = (size_t)blockIdx.x * 256 + threadIdx.x;
  int c = (int)((idx >> 14) & (size_t)(C - 1));
  float a = stats[2 * c], bb = stats[2 * c + 1];
  float4 v = y[idx];
  v.x = fmaf(a, v.x, bb); v.y = fmaf(a, v.y, bb);
  v.z = fmaf(a, v.z, bb); v.w = fmaf(a, v.w, bb);
  v.x = v.x >= 0.f ? v.x : 0.01f * v.x;
  v.y = v.y >= 0.f ? v.y : 0.01f * v.y;
  v.z = v.z >= 0.f ? v.z : 0.01f * v.z;
  v.w = v.w >= 0.f ? v.w : 0.01f * v.w;
  y[idx] = v;
}

// ---------------------------------------------------------------------------
// Final 1x1 conv, register-tiled: 2 rows x 16 co per thread, 128 cin.
// ---------------------------------------------------------------------------
__global__ __launch_bounds__(256) void conv1x1_rt(const float* __restrict__ x,
                                                  const float* __restrict__ Wf_t,
                                                  const float* __restrict__ bfv,
                                                  float* __restrict__ out) {
  constexpr int COT = 16;
  int w = threadIdx.x;
  int h0 = blockIdx.x * 2;
  int g = blockIdx.y & 3;
  int b = blockIdx.y >> 2;
  int co0 = g * COT;
  __shared__ float wsm[128 * COT];
  for (int i = threadIdx.x; i < 128 * COT; i += 256) {
    int ci = i / COT, j = i % COT;
    wsm[i] = Wf_t[ci * 64 + co0 + j];
  }
  __syncthreads();
  float acc[2][COT];
#pragma unroll
  for (int p = 0; p < 2; ++p)
#pragma unroll
    for (int j = 0; j < COT; ++j) acc[p][j] = 0.f;
  const float* xb = x + (size_t)b * 128 * HW_ + h0 * W_ + w;
  for (int ci = 0; ci < 128; ++ci) {
    float x0 = xb[(size_t)ci * HW_];
    float x1 = xb[(size_t)ci * HW_ + W_];
#pragma unroll
    for (int jj = 0; jj < COT / 4; ++jj) {
      float4 wv = *(const float4*)(wsm + ci * COT + jj * 4);
      acc[0][jj * 4 + 0] = fmaf(wv.x, x0, acc[0][jj * 4 + 0]);
      acc[0][jj * 4 + 1] = fmaf(wv.y, x0, acc[0][jj * 4 + 1]);
      acc[0][jj * 4 + 2] = fmaf(wv.z, x0, acc[0][jj * 4 + 2]);
      acc[0][jj * 4 + 3] = fmaf(wv.w, x0, acc[0][jj * 4 + 3]);
      acc[1][jj * 4 + 0] = fmaf(wv.x, x1, acc[1][jj * 4 + 0]);
      acc[1][jj * 4 + 1] = fmaf(wv.y, x1, acc[1][jj * 4 + 1]);
      acc[1][jj * 4 + 2] = fmaf(wv.z, x1, acc[1][jj * 4 + 2]);
      acc[1][jj * 4 + 3] = fmaf(wv.w, x1, acc[1][jj * 4 + 3]);
    }
  }
#pragma unroll
  for (int p = 0; p < 2; ++p)
#pragma unroll
    for (int j = 0; j < COT; ++j)
      out[((size_t)b * 64 + co0 + j) * HW_ + (h0 + p) * W_ + w] =
          acc[p][j] + bfv[co0 + j];
}

__global__ void copy4_kernel(const float4* __restrict__ src, float4* __restrict__ dst) {
  int idx = blockIdx.x * 256 + threadIdx.x;
  dst[idx] = src[idx];
}

// ---------------------------------------------------------------------------
extern "C" void kernel_launch(void* const* d_in, const int* in_sizes, int n_in,
                              void* d_out, int out_size, void* d_ws, size_t ws_size,
                              hipStream_t stream) {
  const float* feat = (const float*)d_in[0];
  const float* mask = (const float*)d_in[1];
  const float *Wl[5], *bl[5], *gl[5], *bel[5];
  for (int l = 0; l < 5; ++l) {
    Wl[l]  = (const float*)d_in[2 + 4 * l];
    bl[l]  = (const float*)d_in[3 + 4 * l];
    gl[l]  = (const float*)d_in[4 + 4 * l];
    bel[l] = (const float*)d_in[5 + 4 * l];
  }
  const float* Wf = (const float*)d_in[22];
  const float* bf = (const float*)d_in[23];

  static const int DIMS[5] = {16, 32, 64, 64, 128};
  static const int DILS[5] = {1, 2, 1, 2, 1};
  static const int CINS[5] = {32, 16, 32, 64, 64};

  // Workspace layout (floats)
  float* ws = (float*)d_ws;
  float* bufA = ws;                                        // 8*128*HW
  float* bufB = bufA + (size_t)B_ * 128 * HW_;             // 8*64*HW
  float* maskA = bufB + (size_t)B_ * 64 * HW_;
  float* maskB = maskA + (size_t)B_ * HW_;
  float* cntb = maskB + (size_t)B_ * HW_;
  float* stats = cntb + (size_t)B_ * HW_;                  // 256
  float* wtr = stats + 256;                                // transposed weights
  float* wtrL[6];
  {
    float* p = wtr;
    for (int l = 0; l < 5; ++l) { wtrL[l] = p; p += DIMS[l] * CINS[l] * 9; }
    wtrL[5] = p;                                           // 1x1: 64*128
  }

  // Transpose all weights up front.
  for (int l = 0; l < 5; ++l) {
    int n = DIMS[l] * CINS[l] * 9;
    transpose_w<<<(n + 255) / 256, 256, 0, stream>>>(Wl[l], wtrL[l], DIMS[l], CINS[l] * 9);
  }
  transpose_w<<<(64 * 128 + 255) / 256, 256, 0, stream>>>(Wf, wtrL[5], 64, 128);

  const float* xin = feat;
  const float* mcur = mask;
  float* fb[2] = {bufA, bufB};
  float* mbuf[2] = {maskA, maskB};

  for (int l = 0; l < 5; ++l) {
    int d = DILS[l], cout = DIMS[l], cin = CINS[l];
    int G = cout / 16;
    float* yout = fb[l & 1];
    float* mnext = mbuf[l & 1];

    hipMemsetAsync(stats, 0, 2 * cout * sizeof(float), stream);
    mask_kernel<<<(B_ * HW_) / 256, 256, 0, stream>>>(mcur, cntb, mnext, d, (float)cin);

    dim3 grid(H_ / 2, B_ * G);
    size_t lds = (size_t)cin * 9 * 16 * sizeof(float);
    switch (cin) {
      case 16: conv3x3_rt<16><<<grid, 256, lds, stream>>>(xin, mcur, cntb, wtrL[l], bl[l], yout, cout, d, G); break;
      case 32: conv3x3_rt<32><<<grid, 256, lds, stream>>>(xin, mcur, cntb, wtrL[l], bl[l], yout, cout, d, G); break;
      case 64: conv3x3_rt<64><<<grid, 256, lds, stream>>>(xin, mcur, cntb, wtrL[l], bl[l], yout, cout, d, G); break;
    }

    stats_kernel<<<dim3(HW_ / 1024, B_ * cout), 256, 0, stream>>>((const float4*)yout, stats, cout);
    bn_prep<<<1, 128, 0, stream>>>(stats, gl[l], bel[l], cout, 1.f / (float)(B_ * HW_));
    size_t nvec = (size_t)B_ * cout * HW_ / 4;
    bn_apply<<<(unsigned)(nvec / 256), 256, 0, stream>>>((float4*)yout, stats, cout);

    xin = yout;
    mcur = mnext;
  }

  conv1x1_rt<<<dim3(H_ / 2, B_ * 4), 256, 0, stream>>>(xin, wtrL[5], bf, (float*)d_out);
  copy4_kernel<<<(B_ * HW_ / 4) / 256, 256, 0, stream>>>(
      (const float4*)mcur, (float4*)d_out + ((size_t)B_ * 64 * HW_) / 4);
}

// Round 4
// 1048.129 us; speedup vs baseline: 19.7432x; 3.2896x over previous
//
#include <hip/hip_runtime.h>
#include <cstddef>

static constexpr int B_ = 8;
static constexpr int H_ = 256;
static constexpr int W_ = 256;
static constexpr int HW_ = H_ * W_;
static constexpr int NPIX = B_ * HW_;

typedef __attribute__((ext_vector_type(8))) short short8;
typedef __attribute__((ext_vector_type(4))) float f32x4;

__device__ __forceinline__ float bf2f(short s) {
  union { unsigned u; float f; } c;
  c.u = ((unsigned)(unsigned short)s) << 16;
  return c.f;
}
__device__ __forceinline__ short f2bf(float f) {
  union { float f; unsigned u; } c; c.f = f;
  unsigned u = c.u;
  unsigned r = u + 0x7FFFu + ((u >> 16) & 1u);   // RNE
  return (short)(r >> 16);
}

// ---------------------------------------------------------------------------
// Mask kernel: cnt = clamp(cin * boxsum3x3_dil(m), 1e-5), mnew = maxpool3x3_dil
// ---------------------------------------------------------------------------
__global__ void mask_kernel(const float* __restrict__ m, float* __restrict__ cnt,
                            float* __restrict__ mnew, int d, float cin) {
  int idx = blockIdx.x * 256 + threadIdx.x;
  int b = idx >> 16;
  int hw = idx & (HW_ - 1);
  int h = hw >> 8, w = hw & (W_ - 1);
  const float* mb = m + b * HW_;
  float s = 0.f, mx = 0.f;
#pragma unroll
  for (int kh = 0; kh < 3; ++kh) {
    int hh = h + (kh - 1) * d;
    if ((unsigned)hh >= (unsigned)H_) continue;
#pragma unroll
    for (int kw = 0; kw < 3; ++kw) {
      int ww = w + (kw - 1) * d;
      if ((unsigned)ww >= (unsigned)W_) continue;
      float v = mb[hh * W_ + ww];
      s += v;
      mx = fmaxf(mx, v);
    }
  }
  cnt[idx] = fmaxf(s * cin, 1e-5f);
  mnew[idx] = mx;
}

// ---------------------------------------------------------------------------
// Weight prepack into MFMA B-fragment order, bf16.
// k-space: k = t*CINP + ci (3x3) or k = ci (1x1), K padded to S*32.
// Fragment element (s, nb, lane, j) <- k = s*32 + (lane>>4)*8 + j,
// n = nb*16 + (lane&15). Zeros for k >= 9*CINP or ci >= CINR.
// ---------------------------------------------------------------------------
__global__ void pack_w(const float* __restrict__ Wsrc, short* __restrict__ pk,
                       int CINP, int CINR, int COUT, int S, int is1x1) {
  int idx = blockIdx.x * 256 + threadIdx.x;
  int NB = COUT >> 4;
  if (idx >= S * NB * 512) return;
  int j = idx & 7;
  int lane = (idx >> 3) & 63;
  int nb = (idx >> 9) % NB;
  int s = idx / (NB << 9);
  int k = s * 32 + ((lane >> 4) << 3) + j;
  int n = (nb << 4) + (lane & 15);
  float v = 0.f;
  if (is1x1) {
    if (k < CINR) v = Wsrc[n * CINR + k];
  } else if (k < 9 * CINP) {
    int t = k / CINP, ci = k % CINP;
    if (ci < CINR) v = Wsrc[(n * CINR + ci) * 9 + t];
  }
  pk[idx] = f2bf(v);
}

// ---------------------------------------------------------------------------
// prep0: feat NCHW fp32 * mask -> NHWC bf16 (32 channels)
// ---------------------------------------------------------------------------
__global__ void prep0(const float* __restrict__ feat, const float* __restrict__ m,
                      short* __restrict__ xm) {
  int pix = blockIdx.x * 256 + threadIdx.x;
  float mv = m[pix];
  int b = pix >> 16, hw = pix & (HW_ - 1);
  const float* fp = feat + (size_t)b * 32 * HW_ + hw;
  short8 ov[4];
#pragma unroll
  for (int k = 0; k < 4; ++k)
#pragma unroll
    for (int c = 0; c < 8; ++c)
      ov[k][c] = f2bf(fp[(size_t)(k * 8 + c) * HW_] * mv);
  short8* dst = (short8*)(xm + (size_t)pix * 32);
#pragma unroll
  for (int k = 0; k < 4; ++k) dst[k] = ov[k];
}

// ---------------------------------------------------------------------------
// BN stats over NHWC bf16 y (C = 8<<c8sh channels): per-channel sum/sumsq.
// ---------------------------------------------------------------------------
__global__ void stats_k(const short* __restrict__ y, float* __restrict__ st, int c8sh) {
  int C8 = 1 << c8sh;
  int g = blockIdx.x * 256 + threadIdx.x;
  int chunk = g & (C8 - 1);
  int stride = (1024 * 256) >> c8sh;
  float s[8] = {0, 0, 0, 0, 0, 0, 0, 0}, q[8] = {0, 0, 0, 0, 0, 0, 0, 0};
  for (int p = g >> c8sh; p < NPIX; p += stride) {
    short8 v = *(const short8*)(y + (((size_t)p << c8sh) + chunk) * 8);
#pragma unroll
    for (int c = 0; c < 8; ++c) { float f = bf2f(v[c]); s[c] += f; q[c] += f * f; }
  }
  __shared__ float bins[256];
  int C = C8 * 8;
  for (int i = threadIdx.x; i < 2 * C; i += 256) bins[i] = 0.f;
  __syncthreads();
#pragma unroll
  for (int c = 0; c < 8; ++c) {
    atomicAdd(&bins[2 * (chunk * 8 + c)], s[c]);
    atomicAdd(&bins[2 * (chunk * 8 + c) + 1], q[c]);
  }
  __syncthreads();
  for (int i = threadIdx.x; i < 2 * C; i += 256) atomicAdd(&st[i], bins[i]);
}

__global__ void bn_prep(float* __restrict__ st, const float* __restrict__ g,
                        const float* __restrict__ be, int C, float invN) {
  int c = threadIdx.x;
  if (c >= C) return;
  float mean = st[2 * c] * invN;
  float var = st[2 * c + 1] * invN - mean * mean;
  float a = g[c] * rsqrtf(var + 1e-5f);
  st[2 * c] = a;
  st[2 * c + 1] = be[c] - a * mean;
}

// ---------------------------------------------------------------------------
// prep_bn: y bf16 NHWC (8<<cish ch) -> BN+LeakyReLU (+mask mult) -> bf16 NHWC
// (8<<cosh ch), zero-padding channels >= 8<<cish.
// ---------------------------------------------------------------------------
__global__ void prep_bn(const short* __restrict__ y, const float* __restrict__ st,
                        const float* __restrict__ m, short* __restrict__ xo,
                        int cish, int cosh) {
  int idx = blockIdx.x * 256 + threadIdx.x;
  int chunk = idx & ((1 << cosh) - 1);
  int pix = idx >> cosh;
  short8 ov = {0, 0, 0, 0, 0, 0, 0, 0};
  if (chunk < (1 << cish)) {
    float mv = m ? m[pix] : 1.f;
    short8 yv = *(const short8*)(y + (((size_t)pix << cish) + chunk) * 8);
#pragma unroll
    for (int c = 0; c < 8; ++c) {
      int cf = chunk * 8 + c;
      float v = fmaf(st[2 * cf], bf2f(yv[c]), st[2 * cf + 1]);
      v = v >= 0.f ? v : 0.01f * v;
      ov[c] = f2bf(v * mv);
    }
  }
  *(short8*)(xo + (size_t)idx * 8) = ov;
}

// ---------------------------------------------------------------------------
// MFMA implicit-GEMM 3x3 dilated conv. NHWC bf16 in/out, no LDS.
// Wave tile: MF*16 pixels x NF*16 cout. All pointers built from clamped
// coordinates (always in-bounds); zpad selected for invalid taps.
// ---------------------------------------------------------------------------
template <int CIN, int COUT, int D, int MF, int NF, int NSPLIT>
__global__ __launch_bounds__(256) void conv3_mfma(
    const short* __restrict__ xm, const short* __restrict__ pk,
    const float* __restrict__ cnt, const float* __restrict__ bias,
    short* __restrict__ y, const short* __restrict__ zpad) {
  constexpr int BM = MF * 16 * (4 / NSPLIT);
  constexpr int NB = COUT / 16;
  constexpr int CC = CIN / 32;

  int lane = threadIdx.x & 63;
  int wv = threadIdx.x >> 6;
  int quad = lane >> 4, l16 = lane & 15;
  int w0 = blockIdx.x * BM;
  int h = blockIdx.y;
  int b = blockIdx.z;
  int nsec = wv % NSPLIT;
  int msec = wv / NSPLIT;
  int mw0 = w0 + msec * MF * 16;
  int nb0 = nsec * NF;

  f32x4 acc[MF][NF];
#pragma unroll
  for (int i = 0; i < MF; ++i)
#pragma unroll
    for (int j = 0; j < NF; ++j) acc[i][j] = (f32x4){0.f, 0.f, 0.f, 0.f};

  const short* pkw = pk + (size_t)(nb0 * 64 + lane) * 8;
  const short* zp8 = zpad + quad * 8;

#pragma unroll
  for (int t = 0; t < 9; ++t) {
    int hh = h + (t / 3 - 1) * D;
    int dw = (t % 3 - 1) * D;
    bool hok = (unsigned)hh < (unsigned)H_;
    int hcl = hok ? hh : 0;                       // clamped: in-bounds always
    const short* rowp = xm + ((size_t)(b * H_ + hcl) * W_) * CIN + quad * 8;
    const short* ap[MF];
#pragma unroll
    for (int i = 0; i < MF; ++i) {
      int ww = mw0 + i * 16 + l16 + dw;
      bool v = hok && ((unsigned)ww < (unsigned)W_);
      int wcl = v ? ww : 0;                       // clamped: in-bounds always
      const short* pin = rowp + (size_t)wcl * CIN;
      ap[i] = v ? pin : zp8;
    }
#pragma unroll
    for (int cc = 0; cc < CC; ++cc) {
      int s = t * CC + cc;
      short8 a[MF], bb[NF];
#pragma unroll
      for (int i = 0; i < MF; ++i) a[i] = *(const short8*)(ap[i] + cc * 32);
#pragma unroll
      for (int j = 0; j < NF; ++j)
        bb[j] = *(const short8*)(pkw + ((size_t)s * NB + j) * 512);
#pragma unroll
      for (int i = 0; i < MF; ++i)
#pragma unroll
        for (int j = 0; j < NF; ++j)
          acc[i][j] = __builtin_amdgcn_mfma_f32_16x16x32_bf16(a[i], bb[j], acc[i][j], 0, 0, 0);
    }
  }

  // Epilogue: /cnt + bias, store NHWC bf16. D-frag: col(n)=lane&15, row(m)=quad*4+r.
  const size_t rowb = (size_t)(b * H_ + h) * W_;
#pragma unroll
  for (int i = 0; i < MF; ++i) {
#pragma unroll
    for (int r = 0; r < 4; ++r) {
      int pw = mw0 + i * 16 + quad * 4 + r;
      float ic = 1.f / cnt[(size_t)b * HW_ + h * W_ + pw];
#pragma unroll
      for (int j = 0; j < NF; ++j) {
        int co = (nb0 + j) * 16 + l16;
        float v = acc[i][j][r] * ic + bias[co];
        y[(rowb + pw) * COUT + co] = f2bf(v);
      }
    }
  }
}

// ---------------------------------------------------------------------------
// Final 1x1 conv: NHWC bf16 (128) -> NCHW fp32 d_out (64), + bias.
// ---------------------------------------------------------------------------
__global__ __launch_bounds__(256) void conv1x1_mfma(
    const short* __restrict__ xf, const short* __restrict__ pk,
    const float* __restrict__ bias, float* __restrict__ out) {
  constexpr int CIN = 128, NB = 4;
  int lane = threadIdx.x & 63, wv = threadIdx.x >> 6;
  int quad = lane >> 4, l16 = lane & 15;
  int w0 = blockIdx.x * 128, h = blockIdx.y, b = blockIdx.z;
  int mw0 = w0 + wv * 32;
  f32x4 acc[2][4];
#pragma unroll
  for (int i = 0; i < 2; ++i)
#pragma unroll
    for (int j = 0; j < 4; ++j) acc[i][j] = (f32x4){0.f, 0.f, 0.f, 0.f};
  const short* base0 = xf + ((size_t)(b * H_ + h) * W_ + mw0 + l16) * CIN + quad * 8;
  const short* pkw = pk + (size_t)lane * 8;
#pragma unroll
  for (int s = 0; s < 4; ++s) {
    short8 a0 = *(const short8*)(base0 + s * 32);
    short8 a1 = *(const short8*)(base0 + 16 * CIN + s * 32);
    short8 bb[4];
#pragma unroll
    for (int j = 0; j < 4; ++j) bb[j] = *(const short8*)(pkw + ((size_t)s * NB + j) * 512);
#pragma unroll
    for (int j = 0; j < 4; ++j) {
      acc[0][j] = __builtin_amdgcn_mfma_f32_16x16x32_bf16(a0, bb[j], acc[0][j], 0, 0, 0);
      acc[1][j] = __builtin_amdgcn_mfma_f32_16x16x32_bf16(a1, bb[j], acc[1][j], 0, 0, 0);
    }
  }
#pragma unroll
  for (int i = 0; i < 2; ++i)
#pragma unroll
    for (int r = 0; r < 4; ++r) {
      int pw = mw0 + i * 16 + quad * 4 + r;
#pragma unroll
      for (int j = 0; j < 4; ++j) {
        int co = j * 16 + l16;
        out[((size_t)b * 64 + co) * HW_ + h * W_ + pw] = acc[i][j][r] + bias[co];
      }
    }
}

__global__ void copy4_kernel(const float4* __restrict__ src, float4* __restrict__ dst) {
  int idx = blockIdx.x * 256 + threadIdx.x;
  dst[idx] = src[idx];
}

// ---------------------------------------------------------------------------
extern "C" void kernel_launch(void* const* d_in, const int* in_sizes, int n_in,
                              void* d_out, int out_size, void* d_ws, size_t ws_size,
                              hipStream_t stream) {
  const float* feat = (const float*)d_in[0];
  const float* mask = (const float*)d_in[1];
  const float *Wl[5], *bl[5], *gl[5], *bel[5];
  for (int l = 0; l < 5; ++l) {
    Wl[l]  = (const float*)d_in[2 + 4 * l];
    bl[l]  = (const float*)d_in[3 + 4 * l];
    gl[l]  = (const float*)d_in[4 + 4 * l];
    bel[l] = (const float*)d_in[5 + 4 * l];
  }
  const float* Wf = (const float*)d_in[22];
  const float* bf = (const float*)d_in[23];

  static const int COUTS[5] = {16, 32, 64, 64, 128};
  static const int CINP[5]  = {32, 32, 32, 64, 64};   // padded GEMM cin
  static const int CINR[5]  = {32, 16, 32, 64, 64};   // real weight cin
  static const int DILS[5]  = {1, 2, 1, 2, 1};
  static const int SST[5]   = {9, 9, 9, 18, 18};      // K-steps = 9*CINP/32
  static const int C8I[5]   = {1, 2, 3, 3, 4};        // Y chunks shift (cout/8)
  static const int C8O[5]   = {2, 2, 3, 3, 4};        // X chunks shift (next cin/8)

  // Workspace layout
  short* X = (short*)d_ws;                         // NPIX*128 bf16 (NHWC)
  short* Y = X + (size_t)NPIX * 128;               // NPIX*128 bf16 (NHWC)
  float* mA = (float*)(Y + (size_t)NPIX * 128);
  float* mB = mA + NPIX;
  float* cb = mB + NPIX;
  float* st = cb + NPIX;                           // 256 floats
  short* zp = (short*)(st + 256);                  // 512 shorts zero pad
  short* pkL[6];
  {
    short* p = zp + 512;
    for (int l = 0; l < 5; ++l) { pkL[l] = p; p += SST[l] * (COUTS[l] >> 4) * 512; }
    pkL[5] = p;                                    // 1x1: 4*4*512
  }

  hipMemsetAsync(zp, 0, 512 * sizeof(short), stream);
  for (int l = 0; l < 5; ++l) {
    int sz = SST[l] * (COUTS[l] >> 4) * 512;
    pack_w<<<sz / 256, 256, 0, stream>>>(Wl[l], pkL[l], CINP[l], CINR[l], COUTS[l], SST[l], 0);
  }
  pack_w<<<4 * 4 * 512 / 256, 256, 0, stream>>>(Wf, pkL[5], 128, 128, 64, 4, 1);

  prep0<<<NPIX / 256, 256, 0, stream>>>(feat, mask, X);

  const float* mcur = mask;

  for (int l = 0; l < 5; ++l) {
    int cout = COUTS[l];
    float* mnext = (l & 1) ? mB : mA;
    mask_kernel<<<NPIX / 256, 256, 0, stream>>>(mcur, cb, mnext, DILS[l], (float)CINR[l]);

    switch (l) {
      case 0: conv3_mfma<32, 16, 1, 4, 1, 1><<<dim3(1, 256, 8), 256, 0, stream>>>(X, pkL[0], cb, bl[0], Y, zp); break;
      case 1: conv3_mfma<32, 32, 2, 4, 2, 1><<<dim3(1, 256, 8), 256, 0, stream>>>(X, pkL[1], cb, bl[1], Y, zp); break;
      case 2: conv3_mfma<32, 64, 1, 2, 4, 1><<<dim3(2, 256, 8), 256, 0, stream>>>(X, pkL[2], cb, bl[2], Y, zp); break;
      case 3: conv3_mfma<64, 64, 2, 2, 4, 1><<<dim3(2, 256, 8), 256, 0, stream>>>(X, pkL[3], cb, bl[3], Y, zp); break;
      case 4: conv3_mfma<64, 128, 1, 2, 4, 2><<<dim3(4, 256, 8), 256, 0, stream>>>(X, pkL[4], cb, bl[4], Y, zp); break;
    }

    hipMemsetAsync(st, 0, 2 * cout * sizeof(float), stream);
    stats_k<<<1024, 256, 0, stream>>>(Y, st, C8I[l]);
    bn_prep<<<1, 128, 0, stream>>>(st, gl[l], bel[l], cout, 1.f / (float)NPIX);

    int c8o = 1 << C8O[l];
    prep_bn<<<(unsigned)((size_t)NPIX * c8o / 256), 256, 0, stream>>>(
        Y, st, l < 4 ? mnext : nullptr, X, C8I[l], C8O[l]);

    mcur = mnext;
  }

  conv1x1_mfma<<<dim3(2, 256, 8), 256, 0, stream>>>(X, pkL[5], bf, (float*)d_out);
  copy4_kernel<<<NPIX / 4 / 256, 256, 0, stream>>>(
      (const float4*)mcur, (float4*)d_out + ((size_t)B_ * 64 * HW_) / 4);
}